// Round 1
// baseline (445.437 us; speedup 1.0000x reference)
//
#include <hip/hip_runtime.h>
#include <math.h>

#define B   32
#define C   512
#define R   32      // C / RATIO
#define HW  4096    // 64*64
#define HALF 256    // C/2

// ---------------- Kernel 1: per-(b,c) mean over H*W ----------------
// One block per (b,c): 4096 contiguous floats = 1024 float4; 256 thr x 4 ld.
__global__ __launch_bounds__(256) void se_mean_kernel(const float* __restrict__ x,
                                                      float* __restrict__ means) {
    const int bc = blockIdx.x;                    // 0 .. B*C-1
    const float4* xp = (const float4*)(x + (size_t)bc * HW);
    const int t = threadIdx.x;
    float s = 0.f;
#pragma unroll
    for (int i = 0; i < 4; ++i) {
        float4 v = xp[t + i * 256];
        s += (v.x + v.y) + (v.z + v.w);
    }
    // wave(64) reduce
#pragma unroll
    for (int off = 32; off > 0; off >>= 1) s += __shfl_down(s, off, 64);
    __shared__ float wsum[4];
    const int lane = t & 63, wid = t >> 6;
    if (lane == 0) wsum[wid] = s;
    __syncthreads();
    if (t == 0) {
        means[bc] = (wsum[0] + wsum[1] + wsum[2] + wsum[3]) * (1.0f / HW);
    }
}

// ---------------- Kernel 2: MLP gates + stable top-256 per batch ----------------
// One block per batch, 512 threads (one per channel).
__global__ __launch_bounds__(512) void se_gate_topk_kernel(const float* __restrict__ means,
                                                           const float* __restrict__ w1,
                                                           const float* __restrict__ w2,
                                                           int* __restrict__ idx_out,
                                                           float* __restrict__ gate_out) {
    const int b = blockIdx.x;
    const int t = threadIdx.x;      // channel
    __shared__ float sm[C];
    __shared__ float sy1[R];
    __shared__ float sy2[C];

    sm[t] = means[b * C + t];
    __syncthreads();

    // y1[r] = relu( sum_c mean[c] * w1[r][c] ), r in [0,32)
    if (t < R) {
        float acc = 0.f;
        for (int c = 0; c < C; ++c) acc += sm[c] * w1[t * C + c];
        sy1[t] = fmaxf(acc, 0.f);
    }
    __syncthreads();

    // y2[c] = sigmoid( sum_r y1[r] * w2[c][r] )
    {
        float acc = 0.f;
#pragma unroll
        for (int r = 0; r < R; ++r) acc += sy1[r] * w2[t * R + r];
        sy2[t] = 1.0f / (1.0f + expf(-acc));
    }
    __syncthreads();

    // stable descending rank == jax.lax.top_k order (ties -> lower index first)
    const float v = sy2[t];
    int rank = 0;
    for (int j = 0; j < C; ++j) {
        float u = sy2[j];
        rank += (u > v) || (u == v && j < t);
    }
    if (rank < HALF) {
        idx_out[b * HALF + rank]  = t;
        gate_out[b * HALF + rank] = v;
    }
}

// ---------------- Kernel 3: gather selected channels, scale by gate ----------------
// One block per (b, k): copy 4096 floats from x[b][idx] * gate.
__global__ __launch_bounds__(256) void se_gather_scale_kernel(const float* __restrict__ x,
                                                              const int* __restrict__ idx,
                                                              const float* __restrict__ gate,
                                                              float* __restrict__ out) {
    const int bk = blockIdx.x;        // 0 .. B*HALF-1
    const int b  = bk >> 8;           // / HALF
    const int ch = idx[bk];
    const float g = gate[bk];
    const float4* src = (const float4*)(x + ((size_t)b * C + ch) * HW);
    float4* dst = (float4*)(out + (size_t)bk * HW);
    const int t = threadIdx.x;
#pragma unroll
    for (int i = 0; i < 4; ++i) {
        float4 v = src[t + i * 256];
        v.x *= g; v.y *= g; v.z *= g; v.w *= g;
        dst[t + i * 256] = v;
    }
}

extern "C" void kernel_launch(void* const* d_in, const int* in_sizes, int n_in,
                              void* d_out, int out_size, void* d_ws, size_t ws_size,
                              hipStream_t stream) {
    const float* x  = (const float*)d_in[0];
    const float* w1 = (const float*)d_in[1];
    const float* w2 = (const float*)d_in[2];
    float* out = (float*)d_out;

    // workspace layout: means (B*C f32) | idx (B*HALF i32) | gate (B*HALF f32)
    float* means = (float*)d_ws;                       // 64 KiB
    int*   idx   = (int*)((char*)d_ws + B * C * 4);    // +32 KiB
    float* gate  = (float*)((char*)d_ws + B * C * 4 + B * HALF * 4); // +32 KiB

    se_mean_kernel<<<B * C, 256, 0, stream>>>(x, means);
    se_gate_topk_kernel<<<B, 512, 0, stream>>>(means, w1, w2, idx, gate);
    se_gather_scale_kernel<<<B * HALF, 256, 0, stream>>>(x, idx, gate, out);
}

// Round 2
// 435.789 us; speedup vs baseline: 1.0221x; 1.0221x over previous
//
#include <hip/hip_runtime.h>
#include <math.h>

#define B    32
#define C    512
#define R    32      // C / RATIO
#define HW   4096    // 64*64
#define HALF 256     // C/2

// ---------------- Kernel 1: per-(b,c) mean over H*W ----------------
// One WAVE per row (4096 floats = 1024 float4; 64 lanes x 16 float4).
// 4 waves per block -> grid = B*C/4 = 4096 blocks.
__global__ __launch_bounds__(256) void se_mean_kernel(const float* __restrict__ x,
                                                      float* __restrict__ means) {
    const int t    = threadIdx.x;
    const int lane = t & 63;
    const int wid  = t >> 6;
    const int row  = blockIdx.x * 4 + wid;        // 0 .. B*C-1
    const float4* xp = (const float4*)(x + (size_t)row * HW);

    float4 v[16];
#pragma unroll
    for (int i = 0; i < 16; ++i) v[i] = xp[lane + 64 * i];
    float s = 0.f;
#pragma unroll
    for (int i = 0; i < 16; ++i) s += (v[i].x + v[i].y) + (v[i].z + v[i].w);

#pragma unroll
    for (int off = 32; off > 0; off >>= 1) s += __shfl_down(s, off, 64);
    if (lane == 0) means[row] = s * (1.0f / HW);
}

// ---------------- Kernel 2: MLP gates + stable top-256 per batch ----------------
// One block per batch, 512 threads.
__global__ __launch_bounds__(512) void se_gate_topk_kernel(const float* __restrict__ means,
                                                           const float* __restrict__ w1,
                                                           const float* __restrict__ w2,
                                                           int* __restrict__ idx_out,
                                                           float* __restrict__ gate_out) {
    const int b = blockIdx.x;
    const int t = threadIdx.x;      // channel / worker id
    __shared__ float sm[C];
    __shared__ float ps[R][17];     // segmented partials, padded
    __shared__ float sy1[R];
    __shared__ float sy2[C];

    sm[t] = means[b * C + t];
    __syncthreads();

    // y1[r] = relu( sum_c mean[c] * w1[r][c] ): 16 segments of 32 channels each
    {
        const int r   = t & 31;
        const int seg = t >> 5;     // 0..15
        const int c0  = seg * 32;
        float acc = 0.f;
#pragma unroll
        for (int i = 0; i < 32; ++i) acc += sm[c0 + i] * w1[r * C + c0 + i];
        ps[r][seg] = acc;
    }
    __syncthreads();
    if (t < R) {
        float acc = 0.f;
#pragma unroll
        for (int s = 0; s < 16; ++s) acc += ps[t][s];
        sy1[t] = fmaxf(acc, 0.f);
    }
    __syncthreads();

    // y2[c] = sigmoid( sum_r y1[r] * w2[c][r] )
    {
        float acc = 0.f;
#pragma unroll
        for (int r = 0; r < R; ++r) acc += sy1[r] * w2[t * R + r];
        sy2[t] = 1.0f / (1.0f + expf(-acc));
    }
    __syncthreads();

    // stable descending rank == jax.lax.top_k (ties -> lower index first)
    const float v = sy2[t];
    const float4* sv = (const float4*)sy2;   // LDS broadcast reads
    int rank = 0;
#pragma unroll 4
    for (int j4 = 0; j4 < C / 4; ++j4) {
        float4 u = sv[j4];
        const int j = j4 * 4;
        rank += (u.x > v) || (u.x == v && (j + 0) < t);
        rank += (u.y > v) || (u.y == v && (j + 1) < t);
        rank += (u.z > v) || (u.z == v && (j + 2) < t);
        rank += (u.w > v) || (u.w == v && (j + 3) < t);
    }
    if (rank < HALF) {
        idx_out[b * HALF + rank]  = t;
        gate_out[b * HALF + rank] = v;
    }
}

// ---------------- Kernel 3: gather selected channels, scale by gate ----------------
// One WAVE per (b,k) output row; 4 waves/block -> grid = B*HALF/4 = 2048.
__global__ __launch_bounds__(256) void se_gather_scale_kernel(const float* __restrict__ x,
                                                              const int* __restrict__ idx,
                                                              const float* __restrict__ gate,
                                                              float* __restrict__ out) {
    const int t    = threadIdx.x;
    const int lane = t & 63;
    const int wid  = t >> 6;
    const int bk   = blockIdx.x * 4 + wid;    // 0 .. B*HALF-1
    const int b    = bk >> 8;                 // / HALF
    const int ch   = idx[bk];
    const float g  = gate[bk];
    const float4* src = (const float4*)(x + ((size_t)b * C + ch) * HW);
    float4* dst = (float4*)(out + (size_t)bk * HW);

#pragma unroll
    for (int i = 0; i < 16; ++i) {
        float4 v = src[lane + 64 * i];
        v.x *= g; v.y *= g; v.z *= g; v.w *= g;
        __builtin_nontemporal_store(v.x, &dst[lane + 64 * i].x);
        __builtin_nontemporal_store(v.y, &dst[lane + 64 * i].y);
        __builtin_nontemporal_store(v.z, &dst[lane + 64 * i].z);
        __builtin_nontemporal_store(v.w, &dst[lane + 64 * i].w);
    }
}

extern "C" void kernel_launch(void* const* d_in, const int* in_sizes, int n_in,
                              void* d_out, int out_size, void* d_ws, size_t ws_size,
                              hipStream_t stream) {
    const float* x  = (const float*)d_in[0];
    const float* w1 = (const float*)d_in[1];
    const float* w2 = (const float*)d_in[2];
    float* out = (float*)d_out;

    // workspace layout: means (B*C f32) | idx (B*HALF i32) | gate (B*HALF f32)
    float* means = (float*)d_ws;
    int*   idx   = (int*)((char*)d_ws + B * C * 4);
    float* gate  = (float*)((char*)d_ws + B * C * 4 + B * HALF * 4);

    se_mean_kernel<<<B * C / 4, 256, 0, stream>>>(x, means);
    se_gate_topk_kernel<<<B, 512, 0, stream>>>(means, w1, w2, idx, gate);
    se_gather_scale_kernel<<<B * HALF / 4, 256, 0, stream>>>(x, idx, gate, out);
}

// Round 3
// 435.079 us; speedup vs baseline: 1.0238x; 1.0016x over previous
//
#include <hip/hip_runtime.h>
#include <math.h>

#define B    32
#define C    512
#define R    32      // C / RATIO
#define HW   4096    // 64*64
#define HALF 256     // C/2

typedef float v4f __attribute__((ext_vector_type(4)));

// ---------------- Kernel 1: per-(b,c) mean over H*W ----------------
// One WAVE per row (4096 floats = 1024 float4; 64 lanes x 16 float4).
// 4 waves per block -> grid = B*C/4 = 4096 blocks.
__global__ __launch_bounds__(256) void se_mean_kernel(const float* __restrict__ x,
                                                      float* __restrict__ means) {
    const int t    = threadIdx.x;
    const int lane = t & 63;
    const int wid  = t >> 6;
    const int row  = blockIdx.x * 4 + wid;        // 0 .. B*C-1
    const v4f* xp = (const v4f*)(x + (size_t)row * HW);

    v4f v[16];
#pragma unroll
    for (int i = 0; i < 16; ++i) v[i] = xp[lane + 64 * i];
    float s = 0.f;
#pragma unroll
    for (int i = 0; i < 16; ++i) s += (v[i].x + v[i].y) + (v[i].z + v[i].w);

#pragma unroll
    for (int off = 32; off > 0; off >>= 1) s += __shfl_down(s, off, 64);
    if (lane == 0) means[row] = s * (1.0f / HW);
}

// ---------------- Kernel 2: MLP gates + stable top-256 per batch ----------------
// One block per batch, 512 threads.
__global__ __launch_bounds__(512) void se_gate_topk_kernel(const float* __restrict__ means,
                                                           const float* __restrict__ w1,
                                                           const float* __restrict__ w2,
                                                           int* __restrict__ idx_out,
                                                           float* __restrict__ gate_out) {
    const int b = blockIdx.x;
    const int t = threadIdx.x;      // channel / worker id
    __shared__ float sm[C];
    __shared__ float ps[R][17];     // segmented partials, padded
    __shared__ float sy1[R];
    __shared__ float sy2[C];

    sm[t] = means[b * C + t];
    __syncthreads();

    // y1[r] = relu( sum_c mean[c] * w1[r][c] ): 16 segments of 32 channels each
    {
        const int r   = t & 31;
        const int seg = t >> 5;     // 0..15
        const int c0  = seg * 32;
        float acc = 0.f;
#pragma unroll
        for (int i = 0; i < 32; ++i) acc += sm[c0 + i] * w1[r * C + c0 + i];
        ps[r][seg] = acc;
    }
    __syncthreads();
    if (t < R) {
        float acc = 0.f;
#pragma unroll
        for (int s = 0; s < 16; ++s) acc += ps[t][s];
        sy1[t] = fmaxf(acc, 0.f);
    }
    __syncthreads();

    // y2[c] = sigmoid( sum_r y1[r] * w2[c][r] )
    {
        float acc = 0.f;
#pragma unroll
        for (int r = 0; r < R; ++r) acc += sy1[r] * w2[t * R + r];
        sy2[t] = 1.0f / (1.0f + expf(-acc));
    }
    __syncthreads();

    // stable descending rank == jax.lax.top_k (ties -> lower index first)
    const float v = sy2[t];
    const v4f* sv = (const v4f*)sy2;   // LDS broadcast reads
    int rank = 0;
#pragma unroll 4
    for (int j4 = 0; j4 < C / 4; ++j4) {
        v4f u = sv[j4];
        const int j = j4 * 4;
        rank += (u.x > v) || (u.x == v && (j + 0) < t);
        rank += (u.y > v) || (u.y == v && (j + 1) < t);
        rank += (u.z > v) || (u.z == v && (j + 2) < t);
        rank += (u.w > v) || (u.w == v && (j + 3) < t);
    }
    if (rank < HALF) {
        idx_out[b * HALF + rank]  = t;
        gate_out[b * HALF + rank] = v;
    }
}

// ---------------- Kernel 3: gather selected channels, scale by gate ----------------
// One WAVE per (b,k) output row; 4 waves/block -> grid = B*HALF/4 = 2048.
// Regular loads (want L3 hits on x populated by K1); single VECTOR nontemporal
// store per float4 (global_store_dwordx4 + nt) so the output stream doesn't
// evict x from L3.
__global__ __launch_bounds__(256) void se_gather_scale_kernel(const float* __restrict__ x,
                                                              const int* __restrict__ idx,
                                                              const float* __restrict__ gate,
                                                              float* __restrict__ out) {
    const int t    = threadIdx.x;
    const int lane = t & 63;
    const int wid  = t >> 6;
    const int bk   = blockIdx.x * 4 + wid;    // 0 .. B*HALF-1
    const int b    = bk >> 8;                 // / HALF
    const int ch   = idx[bk];
    const float g  = gate[bk];
    const v4f* src = (const v4f*)(x + ((size_t)b * C + ch) * HW);
    v4f* dst = (v4f*)(out + (size_t)bk * HW);

#pragma unroll
    for (int i = 0; i < 16; ++i) {
        v4f v = src[lane + 64 * i];
        v *= g;
        __builtin_nontemporal_store(v, &dst[lane + 64 * i]);
    }
}

extern "C" void kernel_launch(void* const* d_in, const int* in_sizes, int n_in,
                              void* d_out, int out_size, void* d_ws, size_t ws_size,
                              hipStream_t stream) {
    const float* x  = (const float*)d_in[0];
    const float* w1 = (const float*)d_in[1];
    const float* w2 = (const float*)d_in[2];
    float* out = (float*)d_out;

    // workspace layout: means (B*C f32) | idx (B*HALF i32) | gate (B*HALF f32)
    float* means = (float*)d_ws;
    int*   idx   = (int*)((char*)d_ws + B * C * 4);
    float* gate  = (float*)((char*)d_ws + B * C * 4 + B * HALF * 4);

    se_mean_kernel<<<B * C / 4, 256, 0, stream>>>(x, means);
    se_gate_topk_kernel<<<B, 512, 0, stream>>>(means, w1, w2, idx, gate);
    se_gather_scale_kernel<<<B * HALF / 4, 256, 0, stream>>>(x, idx, gate, out);
}